// Round 2
// baseline (112.990 us; speedup 1.0000x reference)
//
#include <hip/hip_runtime.h>
#include <math.h>

// Planck*c in J*m (f32 — matches jnp f32 reference math)
#define HCF 1.98644586e-25f

constexpr int BLOCK = 256;
constexpr int RPT   = 2;                     // rays per thread
constexpr int RAYS_PER_BLOCK = BLOCK * RPT;  // 512

// Fused kernel: each block = (ray-group rg) x (theo chunk).
// Stages 256 energy-filtered theo unit vectors in LDS, each thread tracks
// max-dot for RPT rays, uint-atomicMax into ws. The LAST block to finish
// (device counter) performs the acos/exp/mean finalize and writes d_out.
__global__ __launch_bounds__(BLOCK) void refiner_fused_kernel(
    const float* __restrict__ lattice, const float* __restrict__ angle,
    const float* __restrict__ uq_exp,  const int* __restrict__ hkl,
    const float* __restrict__ phi_max_p, const float* __restrict__ e_min_p,
    unsigned* __restrict__ maxenc, unsigned* __restrict__ counter,
    float* __restrict__ out, int n, int m, int nchunks)
{
    __shared__ float4 s_uq[BLOCK];
    const int tid   = threadIdx.x;
    const int chunk = blockIdx.x % nchunks;
    const int rg    = blockIdx.x / nchunks;

    // ---- B_lab = rot(angle) @ inv(prim(lattice))^T, f32, redundant per thread ----
    const float a = lattice[0], b = lattice[1], cc = lattice[2];
    const float cal = cosf(lattice[3]), cbe = cosf(lattice[4]);
    const float cga = cosf(lattice[5]), sga = sinf(lattice[5]);
    const float e3y = (cal - cbe * cga) / sga;
    const float e3z = sqrtf(fmaxf(1.0f - cbe * cbe - e3y * e3y, 1e-12f));
    const float p01 = b * cga, p02 = cc * cbe, p11 = b * sga, p12 = cc * e3y, p22 = cc * e3z;
    // analytic inverse of upper-triangular prim; recip = inv(prim)^T (lower tri)
    const float i00 = 1.0f / a, i11 = 1.0f / p11, i22 = 1.0f / p22;
    const float i01 = -p01 * (i00 * i11);                          // recip[1][0]
    const float i12 = -p12 * (i11 * i22);                          // recip[2][1]
    const float i02 = (p01 * p12 - p02 * p11) * (i00 * i11 * i22); // recip[2][0]
    // rot = Rx(t0) @ Ry(t1) @ Rz(t2)
    const float c0 = cosf(angle[0]), s0 = sinf(angle[0]);
    const float c1 = cosf(angle[1]), s1 = sinf(angle[1]);
    const float c2 = cosf(angle[2]), s2 = sinf(angle[2]);
    const float M00 = c1 * c2,                M01 = -c1 * s2,               M02 = s1;
    const float M10 = c0 * s2 + s0 * s1 * c2, M11 = c0 * c2 - s0 * s1 * s2, M12 = -s0 * c1;
    const float M20 = s0 * s2 - c0 * s1 * c2, M21 = s0 * c2 + c0 * s1 * s2, M22 = c0 * c1;
    // B = M @ recip  (recip rows: [i00,0,0],[i01,i11,0],[i02,i12,i22])
    const float B00 = M00 * i00 + M01 * i01 + M02 * i02;
    const float B01 = M01 * i11 + M02 * i12;
    const float B02 = M02 * i22;
    const float B10 = M10 * i00 + M11 * i01 + M12 * i02;
    const float B11 = M11 * i11 + M12 * i12;
    const float B12 = M12 * i22;
    const float B20 = M20 * i00 + M21 * i01 + M22 * i02;
    const float B21 = M21 * i11 + M22 * i12;
    const float B22 = M22 * i22;

    // ---- stage this chunk's theo unit vectors into LDS (zeros if masked/OOB) ----
    const int ti = chunk * BLOCK + tid;
    float4 v = make_float4(0.f, 0.f, 0.f, 0.f);
    if (ti < m) {
        const float h0 = (float)hkl[3 * ti + 0];
        const float h1 = (float)hkl[3 * ti + 1];
        const float h2 = (float)hkl[3 * ti + 2];
        const float qx = B00 * h0 + B01 * h1 + B02 * h2;
        const float qy = B10 * h0 + B11 * h1 + B12 * h2;
        const float qz = B20 * h0 + B21 * h1 + B22 * h2;
        const float qn = sqrtf(qx * qx + qy * qy + qz * qz);
        const float inv = 1.0f / qn;
        const float ux = qx * inv, uy = qy * inv, uz = qz * inv;
        const float st = fabsf(uz);
        const float energy = HCF * qn / (2.0f * fmaxf(st, 1e-9f));
        if (energy >= e_min_p[0]) v = make_float4(ux, uy, uz, 0.f);
        // masked -> zero vector: dot = 0 -> phi = pi/2 -> exp(-0.5*(phi/phi_max)^2)
        // underflows to exactly 0.0f, same contribution as reference's phi = pi.
    }
    s_uq[tid] = v;
    __syncthreads();

    // ---- per-thread rays ----
    float rx[RPT], ry[RPT], rz[RPT], mx[RPT];
#pragma unroll
    for (int i = 0; i < RPT; ++i) {
        const int ray = rg * RAYS_PER_BLOCK + i * BLOCK + tid;
        float x = 0.f, y = 0.f, z = 0.f;
        if (ray < n) { x = uq_exp[3 * ray]; y = uq_exp[3 * ray + 1]; z = uq_exp[3 * ray + 2]; }
        rx[i] = x; ry[i] = y; rz[i] = z;
        mx[i] = 0.f;  // clamp-at-zero: negative max-dot contributes exactly 0 anyway
    }

#pragma unroll 8
    for (int j = 0; j < BLOCK; ++j) {
        const float4 t = s_uq[j];   // wave-uniform address -> LDS broadcast, no conflict
#pragma unroll
        for (int i = 0; i < RPT; ++i) {
            const float d = rx[i] * t.x + ry[i] * t.y + rz[i] * t.z;
            mx[i] = fmaxf(mx[i], d);
        }
    }

#pragma unroll
    for (int i = 0; i < RPT; ++i) {
        const int ray = rg * RAYS_PER_BLOCK + i * BLOCK + tid;
        if (ray < n) {
            // mx >= 0 so float ordering == uint ordering on the bit pattern
            atomicMax(&maxenc[ray], __float_as_uint(mx[i]));
        }
    }

    // ---- last-block finalize ----
    __shared__ bool s_last;
    __threadfence();                 // make our atomicMax results globally visible
    if (tid == 0) {
        const unsigned c = atomicAdd(counter, 1u);
        s_last = (c == (unsigned)(gridDim.x - 1));
    }
    __syncthreads();
    if (!s_last) return;

    const float inv_pm = 1.0f / phi_max_p[0];
    float acc = 0.f;
    for (int i = tid; i < n; i += BLOCK) {
        // atomic RMW-no-op = device-scope load, bypasses any stale L1
        const unsigned u = atomicMax(&maxenc[i], 0u);
        const float c = fminf(__uint_as_float(u), 1.0f - 1e-6f);
        const float t = acosf(c) * inv_pm;
        acc += expf(-0.5f * t * t);
    }
#pragma unroll
    for (int off = 32; off > 0; off >>= 1) acc += __shfl_down(acc, off, 64);
    __shared__ float s_red[BLOCK / 64];
    if ((tid & 63) == 0) s_red[tid >> 6] = acc;
    __syncthreads();
    if (tid == 0) {
        float tot = 0.f;
#pragma unroll
        for (int k = 0; k < BLOCK / 64; ++k) tot += s_red[k];
        out[0] = tot / (float)n;     // single writer: plain store, no memset needed
    }
}

extern "C" void kernel_launch(void* const* d_in, const int* in_sizes, int n_in,
                              void* d_out, int out_size, void* d_ws, size_t ws_size,
                              hipStream_t stream) {
    const float* lattice = (const float*)d_in[0];
    const float* angle   = (const float*)d_in[1];
    const float* uq_exp  = (const float*)d_in[2];
    const int*   hkl     = (const int*)d_in[3];
    const float* phi_max = (const float*)d_in[4];
    const float* e_min   = (const float*)d_in[5];
    const int n = in_sizes[2] / 3;   // ~5000 exp rays
    const int m = in_sizes[3] / 3;   // ~12.7k hkl

    unsigned* maxenc  = (unsigned*)d_ws;
    unsigned* counter = maxenc + n;

    // zero maxenc + counter in ONE small fill (ws is poisoned 0xAA each call)
    hipMemsetAsync(d_ws, 0, (size_t)(n + 1) * sizeof(unsigned), stream);

    const int nchunks = (m + BLOCK - 1) / BLOCK;
    const int nrg     = (n + RAYS_PER_BLOCK - 1) / RAYS_PER_BLOCK;
    refiner_fused_kernel<<<dim3(nrg * nchunks), dim3(BLOCK), 0, stream>>>(
        lattice, angle, uq_exp, hkl, phi_max, e_min,
        maxenc, counter, (float*)d_out, n, m, nchunks);
}

// Round 3
// 101.179 us; speedup vs baseline: 1.1167x; 1.1167x over previous
//
#include <hip/hip_runtime.h>
#include <math.h>

// Planck*c in J*m (f32 — matches jnp f32 reference math)
#define HCF 1.98644586e-25f

constexpr int BLOCK = 256;
constexpr int RPT   = 2;                     // rays per thread in main kernel
constexpr int RAYS_PER_BLOCK = BLOCK * RPT;  // 512
constexpr int G     = 48;                    // theo groups (grid = G * nrg)

// ---------------- Kernel A: hkl -> lab-frame unit theo vectors ----------------
// Energy-filtered; masked/pad entries become zero vectors (dot=0 -> phi>=pi/2 ->
// exp underflows to exactly 0.0f, bit-identical to reference's phi=pi path).
__global__ __launch_bounds__(256) void theo_kernel(
    const float* __restrict__ lattice, const float* __restrict__ angle,
    const int* __restrict__ hkl, const float* __restrict__ e_min_p,
    float4* __restrict__ theo, int m, int m_pad)
{
    const int ti = blockIdx.x * 256 + threadIdx.x;
    if (ti >= m_pad) return;
    float4 v = make_float4(0.f, 0.f, 0.f, 0.f);
    if (ti < m) {
        // B_lab = rot(angle) @ inv(prim(lattice))^T  (f32, redundant per thread)
        const float a = lattice[0], b = lattice[1], cc = lattice[2];
        const float cal = cosf(lattice[3]), cbe = cosf(lattice[4]);
        const float cga = cosf(lattice[5]), sga = sinf(lattice[5]);
        const float e3y = (cal - cbe * cga) / sga;
        const float e3z = sqrtf(fmaxf(1.0f - cbe * cbe - e3y * e3y, 1e-12f));
        const float p01 = b * cga, p02 = cc * cbe, p11 = b * sga, p12 = cc * e3y, p22 = cc * e3z;
        const float i00 = 1.0f / a, i11 = 1.0f / p11, i22 = 1.0f / p22;
        const float i01 = -p01 * (i00 * i11);
        const float i12 = -p12 * (i11 * i22);
        const float i02 = (p01 * p12 - p02 * p11) * (i00 * i11 * i22);
        const float c0 = cosf(angle[0]), s0 = sinf(angle[0]);
        const float c1 = cosf(angle[1]), s1 = sinf(angle[1]);
        const float c2 = cosf(angle[2]), s2 = sinf(angle[2]);
        const float M00 = c1 * c2,                M01 = -c1 * s2,               M02 = s1;
        const float M10 = c0 * s2 + s0 * s1 * c2, M11 = c0 * c2 - s0 * s1 * s2, M12 = -s0 * c1;
        const float M20 = s0 * s2 - c0 * s1 * c2, M21 = s0 * c2 + c0 * s1 * s2, M22 = c0 * c1;
        const float B00 = M00 * i00 + M01 * i01 + M02 * i02;
        const float B01 = M01 * i11 + M02 * i12;
        const float B02 = M02 * i22;
        const float B10 = M10 * i00 + M11 * i01 + M12 * i02;
        const float B11 = M11 * i11 + M12 * i12;
        const float B12 = M12 * i22;
        const float B20 = M20 * i00 + M21 * i01 + M22 * i02;
        const float B21 = M21 * i11 + M22 * i12;
        const float B22 = M22 * i22;

        const float h0 = (float)hkl[3 * ti + 0];
        const float h1 = (float)hkl[3 * ti + 1];
        const float h2 = (float)hkl[3 * ti + 2];
        const float qx = B00 * h0 + B01 * h1 + B02 * h2;
        const float qy = B10 * h0 + B11 * h1 + B12 * h2;
        const float qz = B20 * h0 + B21 * h1 + B22 * h2;
        const float qn = sqrtf(qx * qx + qy * qy + qz * qz);
        const float inv = 1.0f / qn;
        const float ux = qx * inv, uy = qy * inv, uz = qz * inv;
        const float energy = HCF * qn / (2.0f * fmaxf(fabsf(uz), 1e-9f));
        if (energy >= e_min_p[0]) v = make_float4(ux, uy, uz, 0.f);
    }
    theo[ti] = v;
}

// ---------------- Kernel B: max-dot partials ----------------
// Block (g, rg): rays [rg*512, rg*512+512) vs theos [g*cpg, (g+1)*cpg).
// Theo loads are wave-uniform (SMEM/kcache or L1-broadcast path) — no LDS,
// no barriers, no atomics, no fences. Plain coalesced partial-max stores.
__global__ __launch_bounds__(BLOCK) void maxdot_kernel(
    const float* __restrict__ uq_exp, const float4* __restrict__ theo,
    float* __restrict__ part, int n, int n_pad, int cpg, int nrg)
{
    const int tid = threadIdx.x;
    const int g   = blockIdx.x / nrg;
    const int rg  = blockIdx.x % nrg;

    float rx[RPT], ry[RPT], rz[RPT], mx[RPT];
#pragma unroll
    for (int i = 0; i < RPT; ++i) {
        const int ray = rg * RAYS_PER_BLOCK + i * BLOCK + tid;
        float x = 0.f, y = 0.f, z = 0.f;
        if (ray < n) { x = uq_exp[3 * ray]; y = uq_exp[3 * ray + 1]; z = uq_exp[3 * ray + 2]; }
        rx[i] = x; ry[i] = y; rz[i] = z;
        mx[i] = 0.f;  // clamp-at-zero: negative max-dot contributes exactly 0 anyway
    }

    const float4* __restrict__ th = theo + (size_t)g * cpg;
#pragma unroll 4
    for (int j = 0; j < cpg; ++j) {
        const float4 t = th[j];     // uniform address: scalar/broadcast load
#pragma unroll
        for (int i = 0; i < RPT; ++i) {
            const float d = rx[i] * t.x + ry[i] * t.y + rz[i] * t.z;
            mx[i] = fmaxf(mx[i], d);
        }
    }

#pragma unroll
    for (int i = 0; i < RPT; ++i) {
        const int ray = rg * RAYS_PER_BLOCK + i * BLOCK + tid;   // always < n_pad
        part[(size_t)g * n_pad + ray] = mx[i];
    }
}

// ---------------- Kernel C1: per-ray reduce + Gaussian weight + block sums ----
__global__ __launch_bounds__(256) void weight_kernel(
    const float* __restrict__ part, const float* __restrict__ phi_max_p,
    float* __restrict__ bsums, int n, int n_pad)
{
    const int tid = threadIdx.x;
    const int ray = blockIdx.x * 256 + tid;
    float w = 0.f;
    if (ray < n) {
        float mx = part[ray];
#pragma unroll 4
        for (int g = 1; g < G; ++g) mx = fmaxf(mx, part[(size_t)g * n_pad + ray]);
        const float c = fminf(mx, 1.0f - 1e-6f);   // reference's upper clip
        const float t = acosf(c) / phi_max_p[0];
        w = expf(-0.5f * t * t);
    }
#pragma unroll
    for (int off = 32; off > 0; off >>= 1) w += __shfl_down(w, off, 64);
    __shared__ float s_red[4];
    if ((tid & 63) == 0) s_red[tid >> 6] = w;
    __syncthreads();
    if (tid == 0) bsums[blockIdx.x] = s_red[0] + s_red[1] + s_red[2] + s_red[3];
}

// ---------------- Kernel C2: sum block sums -> mean ----------------
__global__ __launch_bounds__(64) void final_kernel(
    const float* __restrict__ bsums, float* __restrict__ out, int nb, int n)
{
    const int t = threadIdx.x;
    float s = 0.f;
    for (int i = t; i < nb; i += 64) s += bsums[i];
#pragma unroll
    for (int off = 32; off > 0; off >>= 1) s += __shfl_down(s, off, 64);
    if (t == 0) out[0] = s / (float)n;
}

extern "C" void kernel_launch(void* const* d_in, const int* in_sizes, int n_in,
                              void* d_out, int out_size, void* d_ws, size_t ws_size,
                              hipStream_t stream) {
    const float* lattice = (const float*)d_in[0];
    const float* angle   = (const float*)d_in[1];
    const float* uq_exp  = (const float*)d_in[2];
    const int*   hkl     = (const int*)d_in[3];
    const float* phi_max = (const float*)d_in[4];
    const float* e_min   = (const float*)d_in[5];
    const int n = in_sizes[2] / 3;   // ~5000 exp rays
    const int m = in_sizes[3] / 3;   // ~12.7k hkl

    const int cpg   = (((m + G - 1) / G) + 3) & ~3;  // theos per group, mult of 4
    const int m_pad = cpg * G;
    const int nrg   = (n + RAYS_PER_BLOCK - 1) / RAYS_PER_BLOCK;
    const int n_pad = nrg * RAYS_PER_BLOCK;
    const int nbC1  = (n + 255) / 256;

    // ws layout: theo float4[m_pad] | part float[G*n_pad] | bsums float[nbC1]
    float4* theo  = (float4*)d_ws;
    float*  part  = (float*)((char*)d_ws + (size_t)m_pad * sizeof(float4));
    float*  bsums = part + (size_t)G * n_pad;

    theo_kernel<<<dim3((m_pad + 255) / 256), dim3(256), 0, stream>>>(
        lattice, angle, hkl, e_min, theo, m, m_pad);
    maxdot_kernel<<<dim3(G * nrg), dim3(BLOCK), 0, stream>>>(
        uq_exp, theo, part, n, n_pad, cpg, nrg);
    weight_kernel<<<dim3(nbC1), dim3(256), 0, stream>>>(
        part, phi_max, bsums, n, n_pad);
    final_kernel<<<dim3(1), dim3(64), 0, stream>>>(bsums, (float*)d_out, nbC1, n);
}

// Round 4
// 85.211 us; speedup vs baseline: 1.3260x; 1.1874x over previous
//
#include <hip/hip_runtime.h>
#include <math.h>

// Planck*c in J*m (f32 — matches jnp f32 reference math)
#define HCF 1.98644586e-25f

constexpr int BLOCK = 256;
constexpr int RPT   = 4;                     // rays per thread
constexpr int RAYS_PER_BLOCK = BLOCK * RPT;  // 1024
constexpr int CHUNK = 128;                   // theos staged per block

// ---------------- Kernel 1: theo-compute + LDS stage + max-dot partials -------
// Block (chunk, rg): theos [chunk*128, chunk*128+128) vs rays [rg*1024, +1024).
// Theos computed in-block (redundant across the 5 rg's — trivial), staged in
// LDS, read back with wave-uniform addresses (broadcast, conflict-free).
// Partial maxes stored plain+coalesced: every slot written -> no memset needed.
// Energy-masked / OOB theos become zero vectors: dot=0 -> phi>=pi/2 ->
// exp(-0.5*(phi/phi_max)^2) underflows to exactly 0.0f == reference's phi=pi.
__global__ __launch_bounds__(BLOCK) void maxdot_kernel(
    const float* __restrict__ lattice, const float* __restrict__ angle,
    const float* __restrict__ uq_exp,  const int* __restrict__ hkl,
    const float* __restrict__ e_min_p,
    float* __restrict__ part, float* __restrict__ out,
    int n, int n_pad, int m, int nchunks)
{
    __shared__ float4 s_uq[CHUNK];
    const int tid   = threadIdx.x;
    const int chunk = blockIdx.x % nchunks;
    const int rg    = blockIdx.x / nchunks;

    if (blockIdx.x == 0 && tid == 0) out[0] = 0.0f;  // init for kernel 2's atomicAdd

    if (tid < CHUNK) {
        // ---- B_lab = rot(angle) @ inv(prim(lattice))^T, f32 ----
        const float a = lattice[0], b = lattice[1], cc = lattice[2];
        const float cal = cosf(lattice[3]), cbe = cosf(lattice[4]);
        const float cga = cosf(lattice[5]), sga = sinf(lattice[5]);
        const float e3y = (cal - cbe * cga) / sga;
        const float e3z = sqrtf(fmaxf(1.0f - cbe * cbe - e3y * e3y, 1e-12f));
        const float p01 = b * cga, p02 = cc * cbe, p11 = b * sga, p12 = cc * e3y, p22 = cc * e3z;
        // analytic inverse of upper-triangular prim; recip = inv(prim)^T
        const float i00 = 1.0f / a, i11 = 1.0f / p11, i22 = 1.0f / p22;
        const float i01 = -p01 * (i00 * i11);
        const float i12 = -p12 * (i11 * i22);
        const float i02 = (p01 * p12 - p02 * p11) * (i00 * i11 * i22);
        // rot = Rx(t0) @ Ry(t1) @ Rz(t2)
        const float c0 = cosf(angle[0]), s0 = sinf(angle[0]);
        const float c1 = cosf(angle[1]), s1 = sinf(angle[1]);
        const float c2 = cosf(angle[2]), s2 = sinf(angle[2]);
        const float M00 = c1 * c2,                M01 = -c1 * s2,               M02 = s1;
        const float M10 = c0 * s2 + s0 * s1 * c2, M11 = c0 * c2 - s0 * s1 * s2, M12 = -s0 * c1;
        const float M20 = s0 * s2 - c0 * s1 * c2, M21 = s0 * c2 + c0 * s1 * s2, M22 = c0 * c1;
        const float B00 = M00 * i00 + M01 * i01 + M02 * i02;
        const float B01 = M01 * i11 + M02 * i12;
        const float B02 = M02 * i22;
        const float B10 = M10 * i00 + M11 * i01 + M12 * i02;
        const float B11 = M11 * i11 + M12 * i12;
        const float B12 = M12 * i22;
        const float B20 = M20 * i00 + M21 * i01 + M22 * i02;
        const float B21 = M21 * i11 + M22 * i12;
        const float B22 = M22 * i22;

        const int ti = chunk * CHUNK + tid;
        float4 v = make_float4(0.f, 0.f, 0.f, 0.f);
        if (ti < m) {
            const float h0 = (float)hkl[3 * ti + 0];
            const float h1 = (float)hkl[3 * ti + 1];
            const float h2 = (float)hkl[3 * ti + 2];
            const float qx = B00 * h0 + B01 * h1 + B02 * h2;
            const float qy = B10 * h0 + B11 * h1 + B12 * h2;
            const float qz = B20 * h0 + B21 * h1 + B22 * h2;
            const float qn = sqrtf(qx * qx + qy * qy + qz * qz);
            const float inv = 1.0f / qn;
            const float ux = qx * inv, uy = qy * inv, uz = qz * inv;
            const float energy = HCF * qn / (2.0f * fmaxf(fabsf(uz), 1e-9f));
            if (energy >= e_min_p[0]) v = make_float4(ux, uy, uz, 0.f);
        }
        s_uq[tid] = v;
    }
    __syncthreads();

    // ---- per-thread rays ----
    float rx[RPT], ry[RPT], rz[RPT], mx[RPT];
#pragma unroll
    for (int i = 0; i < RPT; ++i) {
        const int ray = rg * RAYS_PER_BLOCK + i * BLOCK + tid;
        float x = 0.f, y = 0.f, z = 0.f;
        if (ray < n) { x = uq_exp[3 * ray]; y = uq_exp[3 * ray + 1]; z = uq_exp[3 * ray + 2]; }
        rx[i] = x; ry[i] = y; rz[i] = z;
        mx[i] = 0.f;  // clamp-at-zero: negative max-dot contributes exactly 0 anyway
    }

#pragma unroll 4
    for (int j = 0; j < CHUNK; ++j) {
        const float4 t = s_uq[j];   // wave-uniform address -> LDS broadcast, no conflict
#pragma unroll
        for (int i = 0; i < RPT; ++i) {
            const float d = rx[i] * t.x + ry[i] * t.y + rz[i] * t.z;
            mx[i] = fmaxf(mx[i], d);
        }
    }

#pragma unroll
    for (int i = 0; i < RPT; ++i) {
        const int ray = rg * RAYS_PER_BLOCK + i * BLOCK + tid;   // always < n_pad
        part[(size_t)chunk * n_pad + ray] = mx[i];
    }
}

// ---------------- Kernel 2: per-ray reduce + Gaussian weight + mean ----------
__global__ __launch_bounds__(256) void weight_kernel(
    const float* __restrict__ part, const float* __restrict__ phi_max_p,
    float* __restrict__ out, int n, int n_pad, int nchunks)
{
    const int tid = threadIdx.x;
    const int ray = blockIdx.x * 256 + tid;
    float w = 0.f;
    if (ray < n) {
        float mx = part[ray];
#pragma unroll 4
        for (int c = 1; c < nchunks; ++c) mx = fmaxf(mx, part[(size_t)c * n_pad + ray]);
        const float cv = fminf(mx, 1.0f - 1e-6f);   // reference's upper clip
        const float t = acosf(cv) / phi_max_p[0];
        w = expf(-0.5f * t * t);
    }
#pragma unroll
    for (int off = 32; off > 0; off >>= 1) w += __shfl_down(w, off, 64);
    __shared__ float s_red[4];
    if ((tid & 63) == 0) s_red[tid >> 6] = w;
    __syncthreads();
    if (tid == 0) {
        const float tot = s_red[0] + s_red[1] + s_red[2] + s_red[3];
        atomicAdd(out, tot / (float)n);   // out zeroed by kernel 1 (kernel-boundary coherent)
    }
}

extern "C" void kernel_launch(void* const* d_in, const int* in_sizes, int n_in,
                              void* d_out, int out_size, void* d_ws, size_t ws_size,
                              hipStream_t stream) {
    const float* lattice = (const float*)d_in[0];
    const float* angle   = (const float*)d_in[1];
    const float* uq_exp  = (const float*)d_in[2];
    const int*   hkl     = (const int*)d_in[3];
    const float* phi_max = (const float*)d_in[4];
    const float* e_min   = (const float*)d_in[5];
    const int n = in_sizes[2] / 3;   // ~5000 exp rays
    const int m = in_sizes[3] / 3;   // ~12.7k hkl

    const int nchunks = (m + CHUNK - 1) / CHUNK;               // ~100
    const int nrg     = (n + RAYS_PER_BLOCK - 1) / RAYS_PER_BLOCK;  // ~5
    const int n_pad   = nrg * RAYS_PER_BLOCK;                  // 5120

    float* part = (float*)d_ws;   // nchunks * n_pad floats (~2 MB), fully overwritten

    maxdot_kernel<<<dim3(nchunks * nrg), dim3(BLOCK), 0, stream>>>(
        lattice, angle, uq_exp, hkl, e_min, part, (float*)d_out, n, n_pad, m, nchunks);
    weight_kernel<<<dim3((n + 255) / 256), dim3(256), 0, stream>>>(
        part, phi_max, (float*)d_out, n, n_pad, nchunks);
}